// Round 3
// baseline (92.861 us; speedup 1.0000x reference)
//
#include <hip/hip_runtime.h>
#include <math.h>

// SpectralCompactnessLoss: B=2, C=32, K=2, N=H*W*D=393216 voxels per batch.
// TWO dispatches:
//   pass1 : channel-split masked sums -> part[2048*2], cntPart[64]; block 0 zeroes ticket
//   pass2 : per-block center reduce (redundant, L2-hot) + per-voxel weighted distance
//           + last-block epilogue via device-scope ticket counter
#define CCH 32
#define KCLS 2
#define BB 2
#define SSEG 32
#define P1_BLOCKS (BB * SSEG * CCH)        // 2048
#define P2_PER_B 768
#define P2_BLOCKS (BB * P2_PER_B)          // 1536

// ws float offsets
#define OFF_PART 0                           // P1_BLOCKS*2 = 4096
#define OFF_CNTP (OFF_PART + P1_BLOCKS * 2)  // 64
#define OFF_LOSS (OFF_CNTP + BB * SSEG)      // P2_BLOCKS*2 = 3072
#define OFF_TICK (OFF_LOSS + P2_BLOCKS * 2)  // 1 (as uint)

__device__ __forceinline__ float waveReduceSum(float v) {
#pragma unroll
    for (int o = 32; o > 0; o >>= 1) v += __shfl_down(v, o);
    return v;
}

// Pass 1: block = (b, s, c); streams one channel-row segment.
__global__ void __launch_bounds__(256) scl_pass1(
    const float* __restrict__ feat, const int* __restrict__ tgt,
    float* __restrict__ part, float* __restrict__ cntPart,
    unsigned int* __restrict__ ticket, int N) {
    if (blockIdx.x == 0 && threadIdx.x == 0) *ticket = 0u;  // arm pass2's epilogue

    const int blk = blockIdx.x;
    const int c = blk & (CCH - 1);
    const int s = (blk >> 5) & (SSEG - 1);
    const int b = blk >> 10;
    const int segVox = N / SSEG;           // 12288
    const int segQ = segVox / 4;           // 3072 -> 12 iters/thread

    const float* fb = feat + ((size_t)(b * CCH + c)) * N + (size_t)s * segVox;
    const int*   tb = tgt + (size_t)b * N + (size_t)s * segVox;

    float s1 = 0.f, st = 0.f, c1 = 0.f;
    for (int q = threadIdx.x; q < segQ; q += 256) {
        const int n = q * 4;
        const int4   t4 = *reinterpret_cast<const int4*>(tb + n);
        const float4 v  = *reinterpret_cast<const float4*>(fb + n);
        const float m1x = t4.x ? 1.f : 0.f;
        const float m1y = t4.y ? 1.f : 0.f;
        const float m1z = t4.z ? 1.f : 0.f;
        const float m1w = t4.w ? 1.f : 0.f;
        st += (v.x + v.y) + (v.z + v.w);
        s1 += v.x * m1x + v.y * m1y + v.z * m1z + v.w * m1w;
        c1 += (m1x + m1y) + (m1z + m1w);
    }

    __shared__ float sm[4][3];
    const int lane = threadIdx.x & 63;
    const int wv   = threadIdx.x >> 6;
    float r1 = waveReduceSum(s1);
    float rt = waveReduceSum(st);
    float rc = waveReduceSum(c1);
    if (lane == 0) { sm[wv][0] = r1; sm[wv][1] = rt; sm[wv][2] = rc; }
    __syncthreads();
    if (threadIdx.x == 0) {
        part[blk * 2 + 0] = sm[0][0] + sm[1][0] + sm[2][0] + sm[3][0];
        part[blk * 2 + 1] = sm[0][1] + sm[1][1] + sm[2][1] + sm[3][1];
        if (c == 0)
            cntPart[b * SSEG + s] = sm[0][2] + sm[1][2] + sm[2][2] + sm[3][2];
    }
}

// Pass 2: center preamble + weighted distance + last-block epilogue.
__global__ void __launch_bounds__(256) scl_pass2(
    const float* __restrict__ feat, const float* __restrict__ pred,
    const int* __restrict__ tgt,
    const float* __restrict__ part, const float* __restrict__ cntPart,
    float* __restrict__ lossPart, unsigned int* __restrict__ ticket,
    float* __restrict__ out, int N) {
    const int blk = blockIdx.x;
    const int b  = (blk >= P2_PER_B) ? 1 : 0;
    const int lb = blk - b * P2_PER_B;
    const int t = threadIdx.x;

    // ---- preamble: redundant per-block center reduction (L2-hot reads) ----
    __shared__ float red[64][4];
    __shared__ float cnt_sm[34];
    __shared__ float ctr[KCLS * CCH];
    if (t < SSEG) cnt_sm[t] = cntPart[b * SSEG + t];
    {
        const int combo = t >> 2;      // c*2 + val
        const int quarter = t & 3;     // 8 segments each
        const int c = combo >> 1;
        const int val = combo & 1;
        const float* p = part + ((size_t)(b * SSEG) * CCH + c) * 2 + val;
        float s = 0.f;
#pragma unroll
        for (int i = 0; i < 8; ++i)
            s += p[(size_t)(quarter * 8 + i) * CCH * 2];
        red[combo][quarter] = s;
    }
    __syncthreads();
    if (t == 0) {
        float c1 = 0.f;
#pragma unroll
        for (int i = 0; i < SSEG; ++i) c1 += cnt_sm[i];
        cnt_sm[32] = c1;
    }
    __syncthreads();
    if (t < CCH) {
        const float c1 = cnt_sm[32];
        const float c0 = (float)N - c1;
        const float s1 = (red[t*2][0] + red[t*2][1]) + (red[t*2][2] + red[t*2][3]);
        const float st = (red[t*2+1][0] + red[t*2+1][1]) + (red[t*2+1][2] + red[t*2+1][3]);
        ctr[t]       = (st - s1) / fmaxf(c0, 1.f);
        ctr[CCH + t] = s1 / fmaxf(c1, 1.f);
    }
    __syncthreads();

    // ---- main: 2 voxels per thread ----
    const int n = (lb * 256 + t) * 2;
    const float* fb = feat + (size_t)b * CCH * N;
    const float* p0 = pred + (size_t)b * KCLS * N;
    const float* p1 = p0 + N;
    const int*   tb = tgt + (size_t)b * N;

    const int2   t2 = *reinterpret_cast<const int2*>(tb + n);
    const float2 a0 = *reinterpret_cast<const float2*>(p0 + n);
    const float2 a1 = *reinterpret_cast<const float2*>(p1 + n);

    float d2x = 0.f, d2y = 0.f;
#pragma unroll
    for (int c = 0; c < CCH; ++c) {
        const float2 v = *reinterpret_cast<const float2*>(fb + (size_t)c * N + n);
        const float c0 = ctr[c], c1 = ctr[CCH + c];
        float d;
        d = v.x - (t2.x ? c1 : c0); d2x += d * d;
        d = v.y - (t2.y ? c1 : c0); d2y += d * d;
    }

    float l0 = 0.f, l1 = 0.f;
    {
        float mx = fmaxf(a0.x, a1.x);
        float e0 = __expf(a0.x - mx), e1 = __expf(a1.x - mx);
        float cf = (t2.x ? e1 : e0) / (e0 + e1);
        float w  = sqrtf(d2x) * cf;
        l0 += t2.x ? 0.f : w; l1 += t2.x ? w : 0.f;
        mx = fmaxf(a0.y, a1.y);
        e0 = __expf(a0.y - mx); e1 = __expf(a1.y - mx);
        cf = (t2.y ? e1 : e0) / (e0 + e1);
        w  = sqrtf(d2y) * cf;
        l0 += t2.y ? 0.f : w; l1 += t2.y ? w : 0.f;
    }

    const int lane = t & 63;
    const int wv   = t >> 6;
    float r0 = waveReduceSum(l0);
    float r1 = waveReduceSum(l1);
    __syncthreads();  // red[] reuse
    if (lane == 0) { red[wv][0] = r0; red[wv][1] = r1; }
    __syncthreads();

    __shared__ bool isLast;
    if (t == 0) {
        lossPart[blk * 2 + 0] = (red[0][0] + red[1][0]) + (red[2][0] + red[3][0]);
        lossPart[blk * 2 + 1] = (red[0][1] + red[1][1]) + (red[2][1] + red[3][1]);
        __threadfence();
        isLast = (atomicAdd(ticket, 1u) == P2_BLOCKS - 1);
    }
    __syncthreads();
    if (!isLast) return;

    // ---- epilogue: only the last block ----
    __threadfence();
    float a00 = 0.f, a01 = 0.f, a10 = 0.f, a11 = 0.f;
    for (int i = t; i < P2_BLOCKS; i += 256) {
        const float l0e = lossPart[i * 2 + 0];
        const float l1e = lossPart[i * 2 + 1];
        if (i < P2_PER_B) { a00 += l0e; a01 += l1e; }
        else              { a10 += l0e; a11 += l1e; }
    }
    float q0 = waveReduceSum(a00);
    float q1 = waveReduceSum(a01);
    float q2 = waveReduceSum(a10);
    float q3 = waveReduceSum(a11);
    __syncthreads();
    if (lane == 0) { red[wv][0] = q0; red[wv][1] = q1; red[wv][2] = q2; red[wv][3] = q3; }
    __syncthreads();
    if (t == 0) {
        float loss[4];
#pragma unroll
        for (int i = 0; i < 4; ++i)
            loss[i] = (red[0][i] + red[1][i]) + (red[2][i] + red[3][i]);
        float cn[4];
        {
            float c1b0 = 0.f, c1b1 = 0.f;
#pragma unroll
            for (int i = 0; i < SSEG; ++i) {
                c1b0 += cntPart[i];
                c1b1 += cntPart[SSEG + i];
            }
            cn[0] = (float)N - c1b0; cn[1] = c1b0;
            cn[2] = (float)N - c1b1; cn[3] = c1b1;
        }
        float total = 0.f, nv = 0.f;
#pragma unroll
        for (int bk = 0; bk < 4; ++bk) {
            const float cl = loss[bk] / fmaxf(cn[bk], 1.f);
            if (cn[bk] >= 2.f) { total += cl; nv += 1.f; }
        }
        out[0] = (nv > 0.f) ? (total / nv) : 0.f;
    }
}

extern "C" void kernel_launch(void* const* d_in, const int* in_sizes, int n_in,
                              void* d_out, int out_size, void* d_ws, size_t ws_size,
                              hipStream_t stream) {
    const float* feat = (const float*)d_in[0];
    const float* pred = (const float*)d_in[1];
    const int*   tgt  = (const int*)d_in[2];
    float* out = (float*)d_out;

    const int totalVox = in_sizes[2];   // B*N
    const int N = totalVox / BB;        // 393216

    float* ws       = (float*)d_ws;
    float* part     = ws + OFF_PART;
    float* cntPart  = ws + OFF_CNTP;
    float* lossPart = ws + OFF_LOSS;
    unsigned int* ticket = (unsigned int*)(ws + OFF_TICK);

    scl_pass1<<<P1_BLOCKS, 256, 0, stream>>>(feat, tgt, part, cntPart, ticket, N);
    scl_pass2<<<P2_BLOCKS, 256, 0, stream>>>(feat, pred, tgt, part, cntPart,
                                             lossPart, ticket, out, N);
}